// Round 2
// baseline (22756.873 us; speedup 1.0000x reference)
//
#include <hip/hip_runtime.h>

#define HW 3136
#define DHW 50176
#define NEL 25690112   // 8*64*16*56*56
#define CNT 401408.0f  // 8*16*56*56

// ---------------------------------------------------------------------------
// Standard 3x3x3 conv, stride 1, pad 1. Block = 448 threads = (8 dd x 56 w) at
// fixed (n, h). LDS double-buffer stages a 10-d-slice x 3-row x 58-col halo
// tile per input channel; register-prefetch pipeline (load->regs, compute,
// regs->LDS, barrier). Optionally applies BN scale/shift + ReLU to the input
// as it is staged (BN_IN) -- padding stays exactly zero.
// ---------------------------------------------------------------------------
template<int NCO, bool BN_IN>
__global__ __launch_bounds__(448) void k_conv3(
    const float* __restrict__ src, const float* __restrict__ wgt,
    const float* __restrict__ bias, const float* __restrict__ scv,
    const float* __restrict__ shv, float* __restrict__ dst)
{
    __shared__ float tile[2][10 * 177];   // slice stride 177 = 3*59 (row pad)
    const int h     = blockIdx.x;         // 0..55
    const int dbase = blockIdx.y << 3;    // 0 or 8
    const int n     = blockIdx.z;         // 0..7
    const int tid   = threadIdx.x;
    const int w0    = tid % 56;
    const int ddl   = tid / 56;           // 0..7

    float acc[NCO];
#pragma unroll
    for (int i = 0; i < NCO; ++i) acc[i] = 0.f;

    const float* sn = src + (size_t)n * 64 * DHW;
    float sreg[4];

    // prologue: stage ci=0 into buffer 0
    {
        const float s0 = BN_IN ? scv[0] : 0.f;
        const float h0 = BN_IN ? shv[0] : 0.f;
#pragma unroll
        for (int k = 0; k < 4; ++k) {
            const int l = tid + k * 448;
            if (l < 1740) {                      // 10 * 174 real elements
                const int dr = l / 174, r = l - dr * 174;
                const int hh = r / 58,  ww = r - hh * 58;
                const int d = dbase - 1 + dr, hq = h + hh - 1, wq = ww - 1;
                float v = 0.f;
                if (((unsigned)d < 16u) & ((unsigned)hq < 56u) & ((unsigned)wq < 56u)) {
                    v = sn[d * HW + hq * 56 + wq];
                    if (BN_IN) v = fmaxf(fmaf(v, s0, h0), 0.f);
                }
                tile[0][dr * 177 + hh * 59 + ww] = v;
            }
        }
    }
    __syncthreads();

#pragma unroll 1
    for (int ci = 0; ci < 64; ++ci) {
        const int buf = ci & 1;
        // prefetch next channel into registers (latency hidden by compute)
        if (ci < 63) {
            const float* scp = sn + (size_t)(ci + 1) * DHW;
            const float s1 = BN_IN ? scv[ci + 1] : 0.f;
            const float h1 = BN_IN ? shv[ci + 1] : 0.f;
#pragma unroll
            for (int k = 0; k < 4; ++k) {
                const int l = tid + k * 448;
                float v = 0.f;
                if (l < 1740) {
                    const int dr = l / 174, r = l - dr * 174;
                    const int hh = r / 58,  ww = r - hh * 58;
                    const int d = dbase - 1 + dr, hq = h + hh - 1, wq = ww - 1;
                    if (((unsigned)d < 16u) & ((unsigned)hq < 56u) & ((unsigned)wq < 56u)) {
                        v = scp[d * HW + hq * 56 + wq];
                        if (BN_IN) v = fmaxf(fmaf(v, s1, h1), 0.f);
                    }
                }
                sreg[k] = v;
            }
        }
        // compute from tile[buf]
        {
            const float* tp = &tile[buf][ddl * 177];
            float val[27];
#pragma unroll
            for (int kd = 0; kd < 3; ++kd)
#pragma unroll
                for (int kh = 0; kh < 3; ++kh)
#pragma unroll
                    for (int kw = 0; kw < 3; ++kw)
                        val[kd * 9 + kh * 3 + kw] = tp[kd * 177 + kh * 59 + w0 + kw];
            const float* wp = wgt + ci * 27;     // block-uniform -> s_load
#pragma unroll
            for (int co = 0; co < NCO; ++co) {
                float s = acc[co];
#pragma unroll
                for (int t = 0; t < 27; ++t)
                    s = fmaf(val[t], wp[co * 1728 + t], s);
                acc[co] = s;
            }
        }
        // drain staged regs to the other buffer
        if (ci < 63) {
#pragma unroll
            for (int k = 0; k < 4; ++k) {
                const int l = tid + k * 448;
                if (l < 1740) {
                    const int dr = l / 174, r = l - dr * 174;
                    const int hh = r / 58,  ww = r - hh * 58;
                    tile[buf ^ 1][dr * 177 + hh * 59 + ww] = sreg[k];
                }
            }
        }
        __syncthreads();
    }

    const int dd = dbase + ddl;
    const size_t sp = (size_t)dd * HW + (size_t)h * 56 + w0;
#pragma unroll
    for (int co = 0; co < NCO; ++co)
        dst[(size_t)(n * NCO + co) * DHW + sp] = acc[co] + bias[co];
}

// ---------------------------------------------------------------------------
// Temporal deformable conv. Block = 448 threads = (8 dd x 56 w) at fixed (n,h).
// LDS stages the FULL 16-deep D column (3 rows x 58 cols halo) per ci, with 4
// zero slices padding each end of D (24 slices total) so temporal taps need no
// masks: i0 clamped to [-3,17] lands all-OOB taps entirely in the zero pad.
// Per-group interp state = 9 LDS base addrs + 9 fracs, recomputed every 8 ci.
// ---------------------------------------------------------------------------
__global__ __launch_bounds__(448) void k_deform(
    const float* __restrict__ x, const float* __restrict__ off,
    const float* __restrict__ wgt, float* __restrict__ dst)
{
    __shared__ float tile[2][24 * 177];   // dz = d + 4; slice stride 177
    const int h     = blockIdx.x;
    const int dbase = blockIdx.y << 3;
    const int n     = blockIdx.z;
    const int tid   = threadIdx.x;
    const int w0    = tid % 56;
    const int ddl   = tid / 56;
    const int dd    = dbase + ddl;

    // zero the D-pad slices (dz 0..3 and 20..23) of both buffers, once
    for (int l = tid; l < 708; l += 448) {
        tile[0][l] = 0.f;        tile[1][l] = 0.f;
        tile[0][3540 + l] = 0.f; tile[1][3540 + l] = 0.f;
    }

    float acc[64];
#pragma unroll
    for (int i = 0; i < 64; ++i) acc[i] = 0.f;

    const float* xn   = x   + (size_t)n * 64 * DHW;
    const float* offn = off + (size_t)n * 8 * (16 * HW);

    int   a0[9];
    float fr[9];
    float sreg[7];

    // prologue: stage ci=0 into buffer 0 (real slices dz 4..19)
    {
#pragma unroll
        for (int k = 0; k < 7; ++k) {
            const int l = tid + k * 448;
            if (l < 2784) {                      // 16 * 174
                const int d  = l / 174, r = l - d * 174;
                const int hh = r / 58,  ww = r - hh * 58;
                const int hq = h + hh - 1, wq = ww - 1;
                float v = 0.f;
                if (((unsigned)hq < 56u) & ((unsigned)wq < 56u))
                    v = xn[d * HW + hq * 56 + wq];
                tile[0][(d + 4) * 177 + hh * 59 + ww] = v;
            }
        }
    }
    __syncthreads();

#pragma unroll 1
    for (int ci = 0; ci < 64; ++ci) {
        const int buf = ci & 1;
        // per-group interpolation state (g changes every 8 channels)
        if ((ci & 7) == 0) {
            const int g = ci >> 3;
            const float* og = offn + (size_t)(g * 16 + dd) * HW;
#pragma unroll
            for (int t = 0; t < 9; ++t) {
                const int kh = t / 3, kw = t - kh * 3;
                int hq = h + kh - 1, wq = w0 + kw - 1;
                hq = min(max(hq, 0), 55);        // clamp: OOB taps read zeros
                wq = min(max(wq, 0), 55);        // from the tile anyway
                const float p  = og[hq * 56 + wq] + (float)dd;
                const float fl = floorf(p);
                fr[t] = p - fl;
                const float flc = fminf(fmaxf(fl, -3.f), 17.f);
                a0[t] = ((int)flc + 3) * 177 + kh * 59 + (w0 + kw);
            }
        }
        // prefetch next channel into registers
        if (ci < 63) {
            const float* xc = xn + (size_t)(ci + 1) * DHW;
#pragma unroll
            for (int k = 0; k < 7; ++k) {
                const int l = tid + k * 448;
                float v = 0.f;
                if (l < 2784) {
                    const int d  = l / 174, r = l - d * 174;
                    const int hh = r / 58,  ww = r - hh * 58;
                    const int hq = h + hh - 1, wq = ww - 1;
                    if (((unsigned)hq < 56u) & ((unsigned)wq < 56u))
                        v = xc[d * HW + hq * 56 + wq];
                }
                sreg[k] = v;
            }
        }
        // compute from tile[buf]
        {
            const float* tp = tile[buf];
            float Gv[27];
#pragma unroll
            for (int t = 0; t < 9; ++t) {
                const float x0 = tp[a0[t]];
                const float x1 = tp[a0[t] + 177];
                const float x2 = tp[a0[t] + 354];
                const float x3 = tp[a0[t] + 531];
                const float f = fr[t], om = 1.f - f;
                Gv[t]      = x0 * om + x1 * f;   // kd = 0
                Gv[9 + t]  = x1 * om + x2 * f;   // kd = 1
                Gv[18 + t] = x2 * om + x3 * f;   // kd = 2
            }
            const float* wp = wgt + ci * 27;     // block-uniform -> s_load
#pragma unroll
            for (int co = 0; co < 64; ++co) {
                float s = acc[co];
#pragma unroll
                for (int t = 0; t < 27; ++t)
                    s = fmaf(Gv[t], wp[co * 1728 + t], s);
                acc[co] = s;
            }
        }
        // drain staged regs to the other buffer
        if (ci < 63) {
#pragma unroll
            for (int k = 0; k < 7; ++k) {
                const int l = tid + k * 448;
                if (l < 2784) {
                    const int d  = l / 174, r = l - d * 174;
                    const int hh = r / 58,  ww = r - hh * 58;
                    tile[buf ^ 1][(d + 4) * 177 + hh * 59 + ww] = sreg[k];
                }
            }
        }
        __syncthreads();
    }

    const size_t sp = (size_t)dd * HW + (size_t)h * 56 + w0;
#pragma unroll
    for (int co = 0; co < 64; ++co)
        dst[(size_t)(n * 64 + co) * DHW + sp] = acc[co];
}

// ---------------- per-channel sum / sumsq reduction ------------------------
__global__ __launch_bounds__(256) void k_stats(
    const float* __restrict__ src, float* __restrict__ sums, float* __restrict__ sqs)
{
    const int c = blockIdx.x, n = blockIdx.y;
    const float* p = src + ((size_t)n * 64 + c) * DHW;
    float s = 0.f, q = 0.f;
    for (int i = threadIdx.x; i < DHW; i += 256) {
        const float v = p[i];
        s += v;
        q = fmaf(v, v, q);
    }
    for (int o = 32; o > 0; o >>= 1) {
        s += __shfl_down(s, o);
        q += __shfl_down(q, o);
    }
    __shared__ float ls[4], lq[4];
    const int wv = threadIdx.x >> 6, lane = threadIdx.x & 63;
    if (lane == 0) { ls[wv] = s; lq[wv] = q; }
    __syncthreads();
    if (threadIdx.x == 0) {
        s = ls[0] + ls[1] + ls[2] + ls[3];
        q = lq[0] + lq[1] + lq[2] + lq[3];
        atomicAdd(&sums[c], s);
        atomicAdd(&sqs[c], q);
    }
}

// ---------------- finalize BN: scale/shift ---------------------------------
__global__ void k_finalize(const float* __restrict__ sums, const float* __restrict__ sqs,
                           const float* __restrict__ gamma, const float* __restrict__ beta,
                           float* __restrict__ scale, float* __restrict__ shift)
{
    const int c = threadIdx.x; // 64 threads
    const float mean = sums[c] / CNT;
    const float var  = sqs[c] / CNT - mean * mean;
    const float sc   = gamma[c] * rsqrtf(var + 1e-5f);
    scale[c] = sc;
    shift[c] = fmaf(-mean, sc, beta[c]);
}

// ---------------- BN + residual + ReLU in place (float4) -------------------
__global__ __launch_bounds__(256) void k_residual(
    float4* __restrict__ out, const float4* __restrict__ x,
    const float* __restrict__ scale, const float* __restrict__ shift)
{
    const int i = blockIdx.x * 256 + threadIdx.x;   // < 6422528
    const int c = (i / 12544) & 63;                  // wave-uniform
    const float sc = scale[c], sh = shift[c];
    float4 v = out[i];
    const float4 xv = x[i];
    v.x = fmaxf(fmaf(v.x, sc, sh) + xv.x, 0.f);
    v.y = fmaxf(fmaf(v.y, sc, sh) + xv.y, 0.f);
    v.z = fmaxf(fmaf(v.z, sc, sh) + xv.z, 0.f);
    v.w = fmaxf(fmaf(v.w, sc, sh) + xv.w, 0.f);
    out[i] = v;
}

extern "C" void kernel_launch(void* const* d_in, const int* in_sizes, int n_in,
                              void* d_out, int out_size, void* d_ws, size_t ws_size,
                              hipStream_t stream) {
    const float* x     = (const float*)d_in[0];
    const float* w_off = (const float*)d_in[1];
    const float* b_off = (const float*)d_in[2];
    const float* w1    = (const float*)d_in[3];
    const float* w2    = (const float*)d_in[4];
    const float* b2    = (const float*)d_in[5];
    const float* g1    = (const float*)d_in[6];
    const float* be1   = (const float*)d_in[7];
    const float* g2    = (const float*)d_in[8];
    const float* be2   = (const float*)d_in[9];

    float* out  = (float*)d_out;
    float* off  = out + NEL;                 // second tuple element
    float* buf1 = (float*)d_ws;              // deform-conv output, NEL floats
    float* st   = buf1 + NEL;                // 512 floats of stats
    // st: 0 sum1 | 64 sq1 | 128 scale1 | 192 shift1 | 256 sum2 | 320 sq2 | 384 scale2 | 448 shift2

    hipMemsetAsync(st, 0, 512 * sizeof(float), stream);

    const dim3 cgrid(56, 2, 8);   // h x dhalf x n, 448-thread blocks

    k_conv3<8, false><<<cgrid, 448, 0, stream>>>(x, w_off, b_off, nullptr, nullptr, off);
    k_deform<<<cgrid, 448, 0, stream>>>(x, off, w1, buf1);
    k_stats<<<dim3(64, 8), 256, 0, stream>>>(buf1, st + 0, st + 64);
    k_finalize<<<1, 64, 0, stream>>>(st + 0, st + 64, g1, be1, st + 128, st + 192);
    k_conv3<64, true><<<cgrid, 448, 0, stream>>>(buf1, w2, b2, st + 128, st + 192, out);
    k_stats<<<dim3(64, 8), 256, 0, stream>>>(out, st + 256, st + 320);
    k_finalize<<<1, 64, 0, stream>>>(st + 256, st + 320, g2, be2, st + 384, st + 448);
    k_residual<<<25088, 256, 0, stream>>>((float4*)out, (const float4*)x, st + 384, st + 448);
}

// Round 3
// 1774.033 us; speedup vs baseline: 12.8278x; 12.8278x over previous
//
#include <hip/hip_runtime.h>

#define HW 3136
#define DHW 50176
#define NEL 25690112   // 8*64*16*56*56
#define CNT 401408.0f  // 8*16*56*56

typedef __attribute__((ext_vector_type(8))) short          short8;
typedef __attribute__((ext_vector_type(8))) unsigned short ushort8;
typedef __attribute__((ext_vector_type(4))) float          f32x4;

__device__ __forceinline__ unsigned f2bf(float f) {
    union { float f; unsigned u; } v; v.f = f;
    return (v.u + 0x7FFFu + ((v.u >> 16) & 1u)) >> 16;   // RNE
}
__device__ __forceinline__ float bf2f(unsigned short u) {
    union { unsigned u; float f; } v; v.u = ((unsigned)u) << 16;
    return v.f;
}

// ---------------------------------------------------------------------------
// x (fp32 NCDHW) -> xt (bf16 channels-last [n][d][h][w][ci])
// block = 256 thr (4 waves); each wave transposes 64-pixel x 64-ci chunks via
// a private LDS tile (row stride 36 dwords, 16B-aligned rows).
// ---------------------------------------------------------------------------
__global__ __launch_bounds__(256) void k_transpose(
    const float* __restrict__ x, unsigned short* __restrict__ xt)
{
    __shared__ unsigned lds[4][64 * 36];
    const int d = blockIdx.x, n = blockIdx.y, z = blockIdx.z;
    const int wave = threadIdx.x >> 6, lane = threadIdx.x & 63;
    const float* xb = x + (size_t)n * 64 * DHW + d * HW;
    unsigned short* xtb = xt + (size_t)(n * 16 + d) * HW * 64;
    unsigned* L = lds[wave];

    for (int c = z * 7 + wave; c < z * 7 + 7 && c < 49; c += 4) {
        const int P = c * 64;
#pragma unroll 4
        for (int cp = 0; cp < 32; ++cp) {
            const float a = xb[(size_t)(2 * cp) * DHW + P + lane];
            const float b = xb[(size_t)(2 * cp + 1) * DHW + P + lane];
            L[lane * 36 + cp] = f2bf(a) | (f2bf(b) << 16);
        }
#pragma unroll
        for (int k = 0; k < 8; ++k) {
            const int r = (lane >> 3) + 8 * k;
            const uint4 v = *(const uint4*)&L[r * 36 + 4 * (lane & 7)];
            *(uint4*)((char*)xtb + (size_t)P * 128 + lane * 16 + k * 1024) = v;
        }
    }
}

// ---------------------------------------------------------------------------
// Weight prep: BtO[t][n(16,8 real)][ci], Bt1/Bt2[t][co][ci]  (bf16)
// ---------------------------------------------------------------------------
__global__ __launch_bounds__(256) void k_wprep(
    const float* __restrict__ w_off, const float* __restrict__ w1,
    const float* __restrict__ w2, unsigned short* __restrict__ BtO,
    unsigned short* __restrict__ Bt1, unsigned short* __restrict__ Bt2)
{
    const int i = blockIdx.x * 256 + threadIdx.x;
    if (i < 27648) {
        const int t = i / 1024, r = i - t * 1024, nn = r >> 6, k = r & 63;
        BtO[i] = (nn < 8) ? (unsigned short)f2bf(w_off[(nn * 64 + k) * 27 + t]) : 0;
    }
    if (i < 110592) {
        const int t = i / 4096, r = i - t * 4096, co = r >> 6, ci = r & 63;
        Bt1[i] = (unsigned short)f2bf(w1[(co * 64 + ci) * 27 + t]);
        Bt2[i] = (unsigned short)f2bf(w2[(co * 64 + ci) * 27 + t]);
    }
}

// ---------------------------------------------------------------------------
// Offset conv (3x3x3, 8 real output channels padded to N=16). Block fixes
// (n,d,h); 4 waves each own one m-frag (16 pixels). A-frags loaded straight
// from global xt (16B, aligned); B-frags from BtO. Output: fp32 NCDHW.
// ---------------------------------------------------------------------------
__global__ __launch_bounds__(256) void k_offc(
    const unsigned short* __restrict__ xt, const unsigned short* __restrict__ BtO,
    const float* __restrict__ b_off, float* __restrict__ offo)
{
    __shared__ float lds[64 * 17];
    const int h = blockIdx.x, d = blockIdx.y, n = blockIdx.z;
    const int wave = threadIdx.x >> 6, lane = threadIdx.x & 63;
    const int lm = lane & 15, quad = lane >> 4;
    const int m = wave * 16 + lm;

    f32x4 acc = {0.f, 0.f, 0.f, 0.f};
#pragma unroll 1
    for (int t = 0; t < 27; ++t) {
        const int kd = t / 9, kh = (t / 3) % 3, kw = t % 3;
        const int dq = d + kd - 1, hq = h + kh - 1;
        if ((unsigned)dq >= 16u || (unsigned)hq >= 56u) continue;   // uniform
        const unsigned short* abase = xt + ((size_t)(n * 16 + dq) * HW + hq * 56) * 64;
        const int wqq = m + kw - 1;
        const bool av = (unsigned)wqq < 56u;
        const unsigned short* ap = abase + (av ? wqq : 0) * 64 + quad * 8;
        const unsigned short* bp = BtO + (t * 16 + lm) * 64 + quad * 8;
#pragma unroll
        for (int ks = 0; ks < 2; ++ks) {
            short8 a = *(const short8*)(ap + ks * 32);
            if (!av) a = (short8)0;
            const short8 b = *(const short8*)(bp + ks * 32);
            acc = __builtin_amdgcn_mfma_f32_16x16x32_bf16(a, b, acc, 0, 0, 0);
        }
    }
#pragma unroll
    for (int r = 0; r < 4; ++r)
        lds[(wave * 16 + quad * 4 + r) * 17 + lm] = acc[r];
    __syncthreads();
    for (int f = threadIdx.x; f < 448; f += 256) {
        const int co = f / 56, w0 = f - co * 56;
        offo[((size_t)(n * 8 + co) * 16 + d) * HW + h * 56 + w0] = lds[w0 * 17 + co] + b_off[co];
    }
}

// ---------------------------------------------------------------------------
// Temporal deformable conv via MFMA. Block fixes (n,d,h); waves = co-slices.
// Per spatial tap (kh,kw): build 3 interpolated A-tiles (kd=0..2) in LDS from
// 4 D-samples of xt (offset field sampled at the SAMPLE pixel), then 3x2x4
// MFMAs per wave. Output out1: fp32 channels-last [pixel][co].
// ---------------------------------------------------------------------------
__global__ __launch_bounds__(256) void k_deform(
    const unsigned short* __restrict__ xt, const float* __restrict__ offo,
    const unsigned short* __restrict__ Bt1, float* __restrict__ out1)
{
    __shared__ __align__(16) unsigned short A3[3 * 64 * 72];  // [kd][m][ci], row 72
    __shared__ float ps[8 * 174];                              // [g][r*58 + c]
    const int h = blockIdx.x, d = blockIdx.y, n = blockIdx.z;
    const int tid = threadIdx.x;
    const int wave = tid >> 6, lane = tid & 63;
    const int lm = lane & 15, quad = lane >> 4;

    for (int idx = tid; idx < 1392; idx += 256) {
        const int g = idx / 174, rem = idx - g * 174, rr = rem / 58, c = rem - rr * 58;
        const int hq = h + rr - 1, wq = c - 1;
        float p = 0.f;
        if (((unsigned)hq < 56u) & ((unsigned)wq < 56u))
            p = offo[((size_t)(n * 8 + g) * 16 + d) * HW + hq * 56 + wq] + (float)d;
        ps[idx] = p;
    }

    f32x4 acc[4];
#pragma unroll
    for (int i = 0; i < 4; ++i) acc[i] = (f32x4){0.f, 0.f, 0.f, 0.f};
    __syncthreads();

#pragma unroll 1
    for (int st = 0; st < 9; ++st) {
        const int kh = st / 3, kw = st - kh * 3;
        const int hq = h + kh - 1;
        const bool rowv = (unsigned)hq < 56u;   // block-uniform
        if (rowv) {
            for (int task = tid; task < 448; task += 256) {
                const int mm = task >> 3, g = task & 7;
                const int wq = mm + kw - 1;
                const bool av = (unsigned)wq < 56u;
                const float p = ps[g * 174 + kh * 58 + (mm + kw)];
                const float fl = floorf(p);
                const float fr = p - fl;
                const int i0 = (int)fl;
                const unsigned short* sb =
                    xt + ((size_t)(n * 16) * HW + hq * 56 + (av ? wq : 0)) * 64 + g * 8;
                float s[4][8];
#pragma unroll
                for (int jj = 0; jj < 4; ++jj) {
                    const int dj = i0 - 1 + jj;
                    const bool ok = av & ((unsigned)dj < 16u);
                    const ushort8 v = *(const ushort8*)(sb + (size_t)(ok ? dj : 0) * (HW * 64));
#pragma unroll
                    for (int e = 0; e < 8; ++e)
                        s[jj][e] = ok ? bf2f(v[e]) : 0.f;
                }
#pragma unroll
                for (int kd = 0; kd < 3; ++kd) {
                    ushort8 o;
#pragma unroll
                    for (int e = 0; e < 8; ++e)
                        o[e] = (unsigned short)f2bf(fmaf(fr, s[kd + 1][e] - s[kd][e], s[kd][e]));
                    *(ushort8*)&A3[(kd * 64 + mm) * 72 + g * 8] = o;
                }
            }
        }
        __syncthreads();
        if (rowv) {
#pragma unroll 1
            for (int kd = 0; kd < 3; ++kd) {
                const int t = kd * 9 + st;
                const unsigned short* bp = Bt1 + (t * 64 + wave * 16 + lm) * 64 + quad * 8;
#pragma unroll
                for (int ks = 0; ks < 2; ++ks) {
                    const short8 b = *(const short8*)(bp + ks * 32);
#pragma unroll
                    for (int mf = 0; mf < 4; ++mf) {
                        const short8 a = *(const short8*)&A3[(kd * 64 + mf * 16 + lm) * 72 + ks * 32 + quad * 8];
                        acc[mf] = __builtin_amdgcn_mfma_f32_16x16x32_bf16(a, b, acc[mf], 0, 0, 0);
                    }
                }
            }
        }
        __syncthreads();
    }

    const size_t pixb = (size_t)(n * 16 + d) * HW + h * 56;
    const int co = wave * 16 + lm;
#pragma unroll
    for (int mf = 0; mf < 4; ++mf)
#pragma unroll
        for (int r = 0; r < 4; ++r) {
            const int mm = mf * 16 + quad * 4 + r;
            if (mm < 56) out1[(pixb + mm) * 64 + co] = acc[mf][r];
        }
}

// ---------------------------------------------------------------------------
// Standard 3x3x3 conv via MFMA, input y1 (bf16 ch-last), 64 output channels.
// Waves = co-slices; A-frags direct from global; epilogue transposes through
// LDS to write fp32 NCDHW (+bias).
// ---------------------------------------------------------------------------
__global__ __launch_bounds__(256) void k_conv2(
    const unsigned short* __restrict__ y1, const unsigned short* __restrict__ Bt2,
    const float* __restrict__ b2, float* __restrict__ out)
{
    __shared__ float lds[64 * 65];
    const int h = blockIdx.x, d = blockIdx.y, n = blockIdx.z;
    const int wave = threadIdx.x >> 6, lane = threadIdx.x & 63;
    const int lm = lane & 15, quad = lane >> 4;

    f32x4 acc[4];
#pragma unroll
    for (int i = 0; i < 4; ++i) acc[i] = (f32x4){0.f, 0.f, 0.f, 0.f};

#pragma unroll 1
    for (int t = 0; t < 27; ++t) {
        const int kd = t / 9, kh = (t / 3) % 3, kw = t % 3;
        const int dq = d + kd - 1, hq = h + kh - 1;
        if ((unsigned)dq >= 16u || (unsigned)hq >= 56u) continue;   // uniform
        const unsigned short* abase = y1 + ((size_t)(n * 16 + dq) * HW + hq * 56) * 64;
        const unsigned short* bp = Bt2 + (t * 64 + wave * 16 + lm) * 64 + quad * 8;
#pragma unroll
        for (int ks = 0; ks < 2; ++ks) {
            const short8 b = *(const short8*)(bp + ks * 32);
#pragma unroll
            for (int mf = 0; mf < 4; ++mf) {
                const int wqq = mf * 16 + lm + kw - 1;
                const bool av = (unsigned)wqq < 56u;
                short8 a = *(const short8*)(abase + (av ? wqq : 0) * 64 + ks * 32 + quad * 8);
                if (!av) a = (short8)0;
                acc[mf] = __builtin_amdgcn_mfma_f32_16x16x32_bf16(a, b, acc[mf], 0, 0, 0);
            }
        }
    }
#pragma unroll
    for (int mf = 0; mf < 4; ++mf)
#pragma unroll
        for (int r = 0; r < 4; ++r)
            lds[(mf * 16 + quad * 4 + r) * 65 + wave * 16 + lm] = acc[mf][r];
    __syncthreads();
    for (int f = threadIdx.x; f < 3584; f += 256) {
        const int co = f / 56, w0 = f - co * 56;
        out[((size_t)(n * 64 + co) * 16 + d) * HW + h * 56 + w0] = lds[w0 * 65 + co] + b2[co];
    }
}

// ---------------- per-channel stats, channels-last fp32 --------------------
__global__ __launch_bounds__(256) void k_stats_cl(
    const float* __restrict__ src, float* __restrict__ sums, float* __restrict__ sqs)
{
    const int ci = threadIdx.x & 63, part = threadIdx.x >> 6;
    const size_t base = (size_t)blockIdx.x * 1024;
    float s = 0.f, q = 0.f;
    for (int i = 0; i < 256; ++i) {
        const float v = src[(base + part + (size_t)i * 4) * 64 + ci];
        s += v; q = fmaf(v, v, q);
    }
    __shared__ float ls[256], lq[256];
    ls[threadIdx.x] = s; lq[threadIdx.x] = q;
    __syncthreads();
    if (threadIdx.x < 64) {
        s = ls[ci] + ls[ci + 64] + ls[ci + 128] + ls[ci + 192];
        q = lq[ci] + lq[ci + 64] + lq[ci + 128] + lq[ci + 192];
        atomicAdd(&sums[ci], s);
        atomicAdd(&sqs[ci], q);
    }
}

// ---------------- per-channel stats, NCDHW fp32 ----------------------------
__global__ __launch_bounds__(256) void k_stats(
    const float* __restrict__ src, float* __restrict__ sums, float* __restrict__ sqs)
{
    const int c = blockIdx.x, n = blockIdx.y;
    const float* p = src + ((size_t)n * 64 + c) * DHW;
    float s = 0.f, q = 0.f;
    for (int i = threadIdx.x; i < DHW; i += 256) {
        const float v = p[i];
        s += v; q = fmaf(v, v, q);
    }
    for (int o = 32; o > 0; o >>= 1) {
        s += __shfl_down(s, o);
        q += __shfl_down(q, o);
    }
    __shared__ float ls[4], lq[4];
    const int wv = threadIdx.x >> 6, lane = threadIdx.x & 63;
    if (lane == 0) { ls[wv] = s; lq[wv] = q; }
    __syncthreads();
    if (threadIdx.x == 0) {
        atomicAdd(&sums[c], ls[0] + ls[1] + ls[2] + ls[3]);
        atomicAdd(&sqs[c],  lq[0] + lq[1] + lq[2] + lq[3]);
    }
}

// ---------------- finalize BN: scale/shift ---------------------------------
__global__ void k_finalize(const float* __restrict__ sums, const float* __restrict__ sqs,
                           const float* __restrict__ gamma, const float* __restrict__ beta,
                           float* __restrict__ scale, float* __restrict__ shift)
{
    const int c = threadIdx.x; // 64 threads
    const float mean = sums[c] / CNT;
    const float var  = sqs[c] / CNT - mean * mean;
    const float sc   = gamma[c] * rsqrtf(var + 1e-5f);
    scale[c] = sc;
    shift[c] = fmaf(-mean, sc, beta[c]);
}

// ------- BN1 + ReLU: out1 (fp32 ch-last) -> y1 (bf16 ch-last) --------------
__global__ __launch_bounds__(256) void k_norm1(
    const float* __restrict__ out1, const float* __restrict__ scale,
    const float* __restrict__ shift, unsigned short* __restrict__ y1)
{
    __shared__ float sc[64], sh[64];
    if (threadIdx.x < 64) { sc[threadIdx.x] = scale[threadIdx.x]; sh[threadIdx.x] = shift[threadIdx.x]; }
    __syncthreads();
    const int i = blockIdx.x * 256 + threadIdx.x;    // quad index < NEL/4
    const float4 v = ((const float4*)out1)[i];
    const int c = (i * 4) & 63;
    const float r0 = fmaxf(fmaf(v.x, sc[c],     sh[c]),     0.f);
    const float r1 = fmaxf(fmaf(v.y, sc[c + 1], sh[c + 1]), 0.f);
    const float r2 = fmaxf(fmaf(v.z, sc[c + 2], sh[c + 2]), 0.f);
    const float r3 = fmaxf(fmaf(v.w, sc[c + 3], sh[c + 3]), 0.f);
    uint2 o;
    o.x = f2bf(r0) | (f2bf(r1) << 16);
    o.y = f2bf(r2) | (f2bf(r3) << 16);
    ((uint2*)y1)[i] = o;
}

// ---------------- BN2 + residual + ReLU in place (float4, NCDHW) -----------
__global__ __launch_bounds__(256) void k_residual(
    float4* __restrict__ out, const float4* __restrict__ x,
    const float* __restrict__ scale, const float* __restrict__ shift)
{
    const int i = blockIdx.x * 256 + threadIdx.x;   // < 6422528
    const int c = (i / 12544) & 63;                  // wave-uniform
    const float sc = scale[c], sh = shift[c];
    float4 v = out[i];
    const float4 xv = x[i];
    v.x = fmaxf(fmaf(v.x, sc, sh) + xv.x, 0.f);
    v.y = fmaxf(fmaf(v.y, sc, sh) + xv.y, 0.f);
    v.z = fmaxf(fmaf(v.z, sc, sh) + xv.z, 0.f);
    v.w = fmaxf(fmaf(v.w, sc, sh) + xv.w, 0.f);
    out[i] = v;
}

extern "C" void kernel_launch(void* const* d_in, const int* in_sizes, int n_in,
                              void* d_out, int out_size, void* d_ws, size_t ws_size,
                              hipStream_t stream) {
    const float* x     = (const float*)d_in[0];
    const float* w_off = (const float*)d_in[1];
    const float* b_off = (const float*)d_in[2];
    const float* w1    = (const float*)d_in[3];
    const float* w2    = (const float*)d_in[4];
    const float* b2    = (const float*)d_in[5];
    const float* g1    = (const float*)d_in[6];
    const float* be1   = (const float*)d_in[7];
    const float* g2    = (const float*)d_in[8];
    const float* be2   = (const float*)d_in[9];

    float* out  = (float*)d_out;            // final: fp32 NCDHW; interim: out1 ch-last
    float* offo = out + NEL;                // off output, fp32 NCDHW [8][8][16][56][56]

    unsigned short* xt  = (unsigned short*)d_ws;        // NEL bf16 (later reused as y1)
    unsigned short* BtO = xt + NEL + 1024;               // slack
    unsigned short* Bt1 = BtO + 27648;
    unsigned short* Bt2 = Bt1 + 110592;
    float* st = (float*)(Bt2 + 110592);
    // st: 0 sum1 | 64 sq1 | 128 sc1 | 192 sh1 | 256 sum2 | 320 sq2 | 384 sc2 | 448 sh2

    hipMemsetAsync(st, 0, 512 * sizeof(float), stream);

    k_transpose<<<dim3(16, 8, 7), 256, 0, stream>>>(x, xt);
    k_wprep<<<432, 256, 0, stream>>>(w_off, w1, w2, BtO, Bt1, Bt2);

    const dim3 cgrid(56, 16, 8);   // h, d, n
    k_offc<<<cgrid, 256, 0, stream>>>(xt, BtO, b_off, offo);
    k_deform<<<cgrid, 256, 0, stream>>>(xt, offo, Bt1, out /*out1 ch-last*/);

    k_stats_cl<<<392, 256, 0, stream>>>(out, st + 0, st + 64);
    k_finalize<<<1, 64, 0, stream>>>(st + 0, st + 64, g1, be1, st + 128, st + 192);
    k_norm1<<<25088, 256, 0, stream>>>(out, st + 128, st + 192, xt /*y1*/);

    k_conv2<<<cgrid, 256, 0, stream>>>(xt /*y1*/, Bt2, b2, out);

    k_stats<<<dim3(64, 8), 256, 0, stream>>>(out, st + 256, st + 320);
    k_finalize<<<1, 64, 0, stream>>>(st + 256, st + 320, g2, be2, st + 384, st + 448);
    k_residual<<<25088, 256, 0, stream>>>((float4*)out, (const float4*)x, st + 384, st + 448);
}

// Round 5
// 1499.718 us; speedup vs baseline: 15.1741x; 1.1829x over previous
//
#include <hip/hip_runtime.h>

#define HW 3136
#define DHW 50176
#define NEL 25690112   // 8*64*16*56*56
#define CNT 401408.0f  // 8*16*56*56

typedef __attribute__((ext_vector_type(8))) short          short8;
typedef __attribute__((ext_vector_type(8))) unsigned short ushort8;
typedef __attribute__((ext_vector_type(4))) float          f32x4;

__device__ __forceinline__ unsigned f2bf(float f) {
    union { float f; unsigned u; } v; v.f = f;
    return (v.u + 0x7FFFu + ((v.u >> 16) & 1u)) >> 16;   // RNE
}
__device__ __forceinline__ float bf2f(unsigned u) {
    union { unsigned u; float f; } v; v.u = u << 16;
    return v.f;
}

// ---------------------------------------------------------------------------
// x (fp32 NCDHW) -> xt (bf16 channels-last [n][d][h][w][ci])
// ---------------------------------------------------------------------------
__global__ __launch_bounds__(256) void k_transpose(
    const float* __restrict__ x, unsigned short* __restrict__ xt)
{
    __shared__ unsigned lds[4][64 * 36];
    const int d = blockIdx.x, n = blockIdx.y, z = blockIdx.z;
    const int wave = threadIdx.x >> 6, lane = threadIdx.x & 63;
    const float* xb = x + (size_t)n * 64 * DHW + d * HW;
    unsigned short* xtb = xt + (size_t)(n * 16 + d) * HW * 64;
    unsigned* L = lds[wave];

    for (int c = z * 7 + wave; c < z * 7 + 7 && c < 49; c += 4) {
        const int P = c * 64;
#pragma unroll 4
        for (int cp = 0; cp < 32; ++cp) {
            const float a = xb[(size_t)(2 * cp) * DHW + P + lane];
            const float b = xb[(size_t)(2 * cp + 1) * DHW + P + lane];
            L[lane * 36 + cp] = f2bf(a) | (f2bf(b) << 16);
        }
#pragma unroll
        for (int k = 0; k < 8; ++k) {
            const int r = (lane >> 3) + 8 * k;
            const uint4 v = *(const uint4*)&L[r * 36 + 4 * (lane & 7)];
            *(uint4*)((char*)xtb + (size_t)P * 128 + lane * 16 + k * 1024) = v;
        }
    }
}

// ---------------------------------------------------------------------------
// Weight prep: BtO[27][16(8 real)][64], Bt1/Bt2[27][64][64]  (bf16)
// ---------------------------------------------------------------------------
__global__ __launch_bounds__(256) void k_wprep(
    const float* __restrict__ w_off, const float* __restrict__ w1,
    const float* __restrict__ w2, unsigned short* __restrict__ BtO,
    unsigned short* __restrict__ Bt1, unsigned short* __restrict__ Bt2)
{
    const int i = blockIdx.x * 256 + threadIdx.x;
    if (i < 27648) {
        const int t = i / 1024, r = i - t * 1024, nn = r >> 6, k = r & 63;
        BtO[i] = (nn < 8) ? (unsigned short)f2bf(w_off[(nn * 64 + k) * 27 + t]) : 0;
    }
    if (i < 110592) {
        const int t = i / 4096, r = i - t * 4096, co = r >> 6, ci = r & 63;
        Bt1[i] = (unsigned short)f2bf(w1[(co * 64 + ci) * 27 + t]);
        Bt2[i] = (unsigned short)f2bf(w2[(co * 64 + ci) * 27 + t]);
    }
}

// ---------------------------------------------------------------------------
// Standard 3x3x3 conv via MFMA, LDS-staged. Block = (h, d, n), 256 thr.
// A-tile: 9 rows (3 dq x 3 hq) x 58 px x 64 ci bf16, row stride 72 shorts.
// Staged ONCE per block (zero-filled OOB), then 27 taps from LDS.
// BN: applies y = relu(fma(v, sc, sh)) to the input while staging (padding
// stays zero -- correct: conv pads in post-BN space).
// NCO=64: each wave owns 2 m-frags x 2 n-frags. NCO=8: wave = m-frag, 1 n-frag.
// ---------------------------------------------------------------------------
template<int NCO, bool BN>
__global__ __launch_bounds__(256) void k_conv(
    const unsigned short* __restrict__ src, const unsigned short* __restrict__ Bt,
    const float* __restrict__ bias, const float* __restrict__ scv,
    const float* __restrict__ shv, float* __restrict__ dst)
{
    __shared__ unsigned short A[538 * 72];   // 9*58=522 slots + 16 overrun pad
    const int h = blockIdx.x, d = blockIdx.y, n = blockIdx.z;
    const int tid = threadIdx.x;
    const int wave = tid >> 6, lane = tid & 63, lm = lane & 15, quad = lane >> 4;
    const int k8 = tid & 7;                  // fixed ci-chunk per thread

    float scr[8], shr[8];
    if constexpr (BN) {
#pragma unroll
        for (int e = 0; e < 8; ++e) { scr[e] = scv[k8 * 8 + e]; shr[e] = shv[k8 * 8 + e]; }
    }

    const unsigned short* snb = src + (size_t)(n * 16) * HW * 64;

    // ---- stage 4176 16B chunks ----
    for (int c = tid; c < 4176; c += 256) {
        const int idx = c >> 3;
        const int row = idx / 58, px = idx - row * 58;
        const int kd = row / 3, kh = row - kd * 3;
        const int dq = d + kd - 1, hq = h + kh - 1, wq = px - 1;
        ushort8 val = (ushort8)0;
        if (((unsigned)dq < 16u) & ((unsigned)hq < 56u) & ((unsigned)wq < 56u)) {
            val = *(const ushort8*)(snb + ((size_t)dq * HW + hq * 56 + wq) * 64 + k8 * 8);
            if constexpr (BN) {
#pragma unroll
                for (int e = 0; e < 8; ++e) {
                    const float f = fmaxf(fmaf(bf2f(val[e]), scr[e], shr[e]), 0.f);
                    val[e] = (unsigned short)f2bf(f);
                }
            }
        }
        *(ushort8*)&A[(size_t)idx * 72 + k8 * 8] = val;
    }
    __syncthreads();

    constexpr int NB  = (NCO == 8) ? 16 : 64;
    constexpr int NFm = (NCO == 8) ? 1 : 2;
    constexpr int NFn = (NCO == 8) ? 1 : 2;
    const int mf0 = (NCO == 8) ? wave : (wave & 1) * 2;
    const int nf0 = (NCO == 8) ? 0 : (wave >> 1) * 2;

    f32x4 acc[NFm][NFn];
#pragma unroll
    for (int i = 0; i < NFm; ++i)
#pragma unroll
        for (int j = 0; j < NFn; ++j) acc[i][j] = (f32x4){0.f, 0.f, 0.f, 0.f};

    // ---- 27-tap K-loop, B software-pipelined ----
    short8 bc[2][NFn];
#pragma unroll
    for (int ks = 0; ks < 2; ++ks)
#pragma unroll
        for (int nf = 0; nf < NFn; ++nf)
            bc[ks][nf] = *(const short8*)(Bt + ((size_t)0 * NB + (nf0 + nf) * 16 + lm) * 64 + ks * 32 + quad * 8);

#pragma unroll 1
    for (int t = 0; t < 27; ++t) {
        short8 bnx[2][NFn];
        if (t < 26) {
#pragma unroll
            for (int ks = 0; ks < 2; ++ks)
#pragma unroll
                for (int nf = 0; nf < NFn; ++nf)
                    bnx[ks][nf] = *(const short8*)(Bt + ((size_t)(t + 1) * NB + (nf0 + nf) * 16 + lm) * 64 + ks * 32 + quad * 8);
        }
        const int kd = t / 9, r9 = t - kd * 9, kh = r9 / 3, kw = r9 - kh * 3;
        const int rowb = (kd * 3 + kh) * 58 + kw;
        short8 a[2][NFm];
#pragma unroll
        for (int ks = 0; ks < 2; ++ks)
#pragma unroll
            for (int mf = 0; mf < NFm; ++mf)
                a[ks][mf] = *(const short8*)&A[(size_t)(rowb + (mf0 + mf) * 16 + lm) * 72 + ks * 32 + quad * 8];
#pragma unroll
        for (int ks = 0; ks < 2; ++ks)
#pragma unroll
            for (int mf = 0; mf < NFm; ++mf)
#pragma unroll
                for (int nf = 0; nf < NFn; ++nf)
                    acc[mf][nf] = __builtin_amdgcn_mfma_f32_16x16x32_bf16(a[ks][mf], bc[ks][nf], acc[mf][nf], 0, 0, 0);
        if (t < 26) {
#pragma unroll
            for (int ks = 0; ks < 2; ++ks)
#pragma unroll
                for (int nf = 0; nf < NFn; ++nf)
                    bc[ks][nf] = bnx[ks][nf];
        }
    }

    // ---- epilogue: LDS transpose -> fp32 NCDHW + bias ----
    __syncthreads();
    float* E = (float*)A;
    constexpr int CSTR = (NCO == 64) ? 65 : 17;
#pragma unroll
    for (int mf = 0; mf < NFm; ++mf)
#pragma unroll
        for (int nf = 0; nf < NFn; ++nf)
#pragma unroll
            for (int r = 0; r < 4; ++r) {
                const int mm = (mf0 + mf) * 16 + quad * 4 + r;
                if (mm < 56) E[mm * CSTR + (nf0 + nf) * 16 + lm] = acc[mf][nf][r];
            }
    __syncthreads();
    for (int f = tid; f < 56 * NCO; f += 256) {
        const int co = f / 56, w0 = f - co * 56;
        dst[((size_t)(n * NCO + co) * 16 + d) * HW + h * 56 + w0] = E[w0 * CSTR + co] + bias[co];
    }
}

// ---------------------------------------------------------------------------
// Temporal deformable conv. Same skeleton as k_conv<64>, but the staging
// phase BUILDS the interpolated field: row (kd, hq) holds
// g_kd[n, :, d, hq, :] = lerp of xt along D at pos = off(d,hq,wq)+d+kd-1.
// The offset is sampled at the SAMPLE pixel, so the tile is consumer-
// independent and built once per block. Output: bf16 ch-last [pixel][co].
// ---------------------------------------------------------------------------
__global__ __launch_bounds__(256) void k_deform(
    const unsigned short* __restrict__ xt, const float* __restrict__ offo,
    const unsigned short* __restrict__ Bt, unsigned short* __restrict__ out1)
{
    __shared__ unsigned short A[538 * 72];
    const int h = blockIdx.x, d = blockIdx.y, n = blockIdx.z;
    const int tid = threadIdx.x;
    const int wave = tid >> 6, lane = tid & 63, lm = lane & 15, quad = lane >> 4;

    // ---- prefetch the 6 offset values this thread needs ----
    float pv[6];
#pragma unroll
    for (int it = 0; it < 6; ++it) {
        const int c = tid + it * 256;
        float p = 0.f;
        if (c < 1392) {
            const int g = c / 174, rem = c - g * 174, hq3 = rem / 58, px = rem - hq3 * 58;
            const int habs = h + hq3 - 1, wq = px - 1;
            if (((unsigned)habs < 56u) & ((unsigned)wq < 56u))
                p = offo[((size_t)(n * 8 + g) * 16 + d) * HW + habs * 56 + wq] + (float)d;
        }
        pv[it] = p;
    }

    // ---- gather + lerp staging: 1392 tasks build all 9 (kd,hq) rows ----
#pragma unroll 2
    for (int it = 0; it < 6; ++it) {
        const int c = tid + it * 256;
        if (c >= 1392) break;
        const int g = c / 174, rem = c - g * 174, hq3 = rem / 58, px = rem - hq3 * 58;
        const int habs = h + hq3 - 1, wq = px - 1;
        ushort8 o0 = (ushort8)0, o1 = (ushort8)0, o2 = (ushort8)0;
        if (((unsigned)habs < 56u) & ((unsigned)wq < 56u)) {
            const float p = pv[it];
            const float fl = floorf(p);
            const float fr = p - fl;
            const int i0 = (int)fl;
            const unsigned short* cb = xt + ((size_t)(n * 16) * HW + habs * 56 + wq) * 64 + g * 8;
            float s[4][8];
#pragma unroll
            for (int j = 0; j < 4; ++j) {
                const int dj = i0 - 1 + j;
                const bool ok = (unsigned)dj < 16u;
                const ushort8 v = *(const ushort8*)(cb + (size_t)(ok ? dj : 0) * (HW * 64));
#pragma unroll
                for (int e = 0; e < 8; ++e) s[j][e] = ok ? bf2f(v[e]) : 0.f;
            }
#pragma unroll
            for (int e = 0; e < 8; ++e) {
                o0[e] = (unsigned short)f2bf(fmaf(fr, s[1][e] - s[0][e], s[0][e]));
                o1[e] = (unsigned short)f2bf(fmaf(fr, s[2][e] - s[1][e], s[1][e]));
                o2[e] = (unsigned short)f2bf(fmaf(fr, s[3][e] - s[2][e], s[2][e]));
            }
        }
        const int sl = hq3 * 58 + px;
        *(ushort8*)&A[(size_t)(sl          ) * 72 + g * 8] = o0;   // kd=0 rows 0..2
        *(ushort8*)&A[(size_t)(sl + 3 * 58 ) * 72 + g * 8] = o1;   // kd=1 rows 3..5
        *(ushort8*)&A[(size_t)(sl + 6 * 58 ) * 72 + g * 8] = o2;   // kd=2 rows 6..8
    }
    __syncthreads();

    const int mf0 = (wave & 1) * 2, nf0 = (wave >> 1) * 2;
    f32x4 acc[2][2];
#pragma unroll
    for (int i = 0; i < 2; ++i)
#pragma unroll
        for (int j = 0; j < 2; ++j) acc[i][j] = (f32x4){0.f, 0.f, 0.f, 0.f};

    short8 bc[2][2];
#pragma unroll
    for (int ks = 0; ks < 2; ++ks)
#pragma unroll
        for (int nf = 0; nf < 2; ++nf)
            bc[ks][nf] = *(const short8*)(Bt + ((size_t)0 * 64 + (nf0 + nf) * 16 + lm) * 64 + ks * 32 + quad * 8);

#pragma unroll 1
    for (int t = 0; t < 27; ++t) {
        short8 bnx[2][2];
        if (t < 26) {
#pragma unroll
            for (int ks = 0; ks < 2; ++ks)
#pragma unroll
                for (int nf = 0; nf < 2; ++nf)
                    bnx[ks][nf] = *(const short8*)(Bt + ((size_t)(t + 1) * 64 + (nf0 + nf) * 16 + lm) * 64 + ks * 32 + quad * 8);
        }
        const int kd = t / 9, r9 = t - kd * 9, kh = r9 / 3, kw = r9 - kh * 3;
        const int rowb = (kd * 3 + kh) * 58 + kw;
        short8 a[2][2];
#pragma unroll
        for (int ks = 0; ks < 2; ++ks)
#pragma unroll
            for (int mf = 0; mf < 2; ++mf)
                a[ks][mf] = *(const short8*)&A[(size_t)(rowb + (mf0 + mf) * 16 + lm) * 72 + ks * 32 + quad * 8];
#pragma unroll
        for (int ks = 0; ks < 2; ++ks)
#pragma unroll
            for (int mf = 0; mf < 2; ++mf)
#pragma unroll
                for (int nf = 0; nf < 2; ++nf)
                    acc[mf][nf] = __builtin_amdgcn_mfma_f32_16x16x32_bf16(a[ks][mf], bc[ks][nf], acc[mf][nf], 0, 0, 0);
        if (t < 26) {
#pragma unroll
            for (int ks = 0; ks < 2; ++ks)
#pragma unroll
                for (int nf = 0; nf < 2; ++nf)
                    bc[ks][nf] = bnx[ks][nf];
        }
    }

    // ---- epilogue: bf16 tile in LDS -> coalesced ch-last stores ----
    __syncthreads();
#pragma unroll
    for (int mf = 0; mf < 2; ++mf)
#pragma unroll
        for (int nf = 0; nf < 2; ++nf)
#pragma unroll
            for (int r = 0; r < 4; ++r) {
                const int mm = (mf0 + mf) * 16 + quad * 4 + r;
                if (mm < 56)
                    A[mm * 72 + (nf0 + nf) * 16 + lm] = (unsigned short)f2bf(acc[mf][nf][r]);
            }
    __syncthreads();
    const size_t pixb = ((size_t)(n * 16) + d) * HW + h * 56;
    for (int c = tid; c < 448; c += 256) {
        const int px = c >> 3, kk = c & 7;
        *(uint4*)(out1 + (pixb + px) * 64 + kk * 8) = *(const uint4*)&A[px * 72 + kk * 8];
    }
}

// ---------------- per-channel stats over bf16 ch-last ----------------------
__global__ __launch_bounds__(256) void k_stats_bf16(
    const unsigned short* __restrict__ src, float* __restrict__ sums, float* __restrict__ sqs)
{
    const int c4 = threadIdx.x & 15, part = threadIdx.x >> 4;   // 16 ci-quads, 16 parts
    const size_t base = (size_t)blockIdx.x * 1024;
    float s[4] = {0.f, 0.f, 0.f, 0.f}, q[4] = {0.f, 0.f, 0.f, 0.f};
#pragma unroll 4
    for (int i = 0; i < 64; ++i) {
        const size_t pix = base + part + (size_t)i * 16;
        const uint2 v = *(const uint2*)(src + pix * 64 + c4 * 4);
        const float f0 = bf2f(v.x & 0xffffu), f1 = bf2f(v.x >> 16);
        const float f2 = bf2f(v.y & 0xffffu), f3 = bf2f(v.y >> 16);
        s[0] += f0; q[0] = fmaf(f0, f0, q[0]);
        s[1] += f1; q[1] = fmaf(f1, f1, q[1]);
        s[2] += f2; q[2] = fmaf(f2, f2, q[2]);
        s[3] += f3; q[3] = fmaf(f3, f3, q[3]);
    }
    __shared__ float S[64], Q[64];
    if (threadIdx.x < 64) { S[threadIdx.x] = 0.f; Q[threadIdx.x] = 0.f; }
    __syncthreads();
#pragma unroll
    for (int e = 0; e < 4; ++e) {
        atomicAdd(&S[c4 * 4 + e], s[e]);
        atomicAdd(&Q[c4 * 4 + e], q[e]);
    }
    __syncthreads();
    if (threadIdx.x < 64) {
        atomicAdd(&sums[threadIdx.x], S[threadIdx.x]);
        atomicAdd(&sqs[threadIdx.x],  Q[threadIdx.x]);
    }
}

// ---------------- per-channel stats, NCDHW fp32 ----------------------------
__global__ __launch_bounds__(256) void k_stats(
    const float* __restrict__ src, float* __restrict__ sums, float* __restrict__ sqs)
{
    const int c = blockIdx.x, n = blockIdx.y;
    const float* p = src + ((size_t)n * 64 + c) * DHW;
    float s = 0.f, q = 0.f;
    for (int i = threadIdx.x; i < DHW; i += 256) {
        const float v = p[i];
        s += v; q = fmaf(v, v, q);
    }
    for (int o = 32; o > 0; o >>= 1) {
        s += __shfl_down(s, o);
        q += __shfl_down(q, o);
    }
    __shared__ float ls[4], lq[4];
    const int wv = threadIdx.x >> 6, lane = threadIdx.x & 63;
    if (lane == 0) { ls[wv] = s; lq[wv] = q; }
    __syncthreads();
    if (threadIdx.x == 0) {
        atomicAdd(&sums[c], ls[0] + ls[1] + ls[2] + ls[3]);
        atomicAdd(&sqs[c],  lq[0] + lq[1] + lq[2] + lq[3]);
    }
}

// ---------------- finalize BN: scale/shift ---------------------------------
__global__ void k_finalize(const float* __restrict__ sums, const float* __restrict__ sqs,
                           const float* __restrict__ gamma, const float* __restrict__ beta,
                           float* __restrict__ scale, float* __restrict__ shift)
{
    const int c = threadIdx.x; // 64 threads
    const float mean = sums[c] / CNT;
    const float var  = sqs[c] / CNT - mean * mean;
    const float sc   = gamma[c] * rsqrtf(var + 1e-5f);
    scale[c] = sc;
    shift[c] = fmaf(-mean, sc, beta[c]);
}

// -------- BN2 + residual + ReLU: dst = relu(bn(raw) + x)  (float4) ---------
__global__ __launch_bounds__(256) void k_residual(
    float4* __restrict__ dst, const float4* __restrict__ raw,
    const float4* __restrict__ x,
    const float* __restrict__ scale, const float* __restrict__ shift)
{
    const int i = blockIdx.x * 256 + threadIdx.x;   // < 6422528
    const int c = (i / 12544) & 63;                  // wave-uniform
    const float sc = scale[c], sh = shift[c];
    float4 v = raw[i];
    const float4 xv = x[i];
    v.x = fmaxf(fmaf(v.x, sc, sh) + xv.x, 0.f);
    v.y = fmaxf(fmaf(v.y, sc, sh) + xv.y, 0.f);
    v.z = fmaxf(fmaf(v.z, sc, sh) + xv.z, 0.f);
    v.w = fmaxf(fmaf(v.w, sc, sh) + xv.w, 0.f);
    dst[i] = v;
}

extern "C" void kernel_launch(void* const* d_in, const int* in_sizes, int n_in,
                              void* d_out, int out_size, void* d_ws, size_t ws_size,
                              hipStream_t stream) {
    const float* x     = (const float*)d_in[0];
    const float* w_off = (const float*)d_in[1];
    const float* b_off = (const float*)d_in[2];
    const float* w1    = (const float*)d_in[3];
    const float* w2    = (const float*)d_in[4];
    const float* b2    = (const float*)d_in[5];
    const float* g1    = (const float*)d_in[6];
    const float* be1   = (const float*)d_in[7];
    const float* g2    = (const float*)d_in[8];
    const float* be2   = (const float*)d_in[9];

    // ---- buffer plan ----
    // d_out: [0, 2*NEL) bytes      : out1 (deform result, bf16 ch-last) -- dead after k_conv<64>
    //        byte 52,000,000       : weight blocks (bf16) -- dead after k_conv<64>
    //        [4*NEL, ...) bytes    : off output (fp32, final)
    //        [0, 4*NEL) bytes      : final out (fp32), written LAST by k_residual
    //        (k_residual clobbers out1+weights; both dead by then. NOTHING live
    //         in d_out is read by k_residual -- st lives in d_ws. Round-4 bug fixed.)
    // d_ws:  [0, 2*NEL) bytes      : xt (bf16 ch-last x) -- dead after k_deform
    //        [0, 4*NEL) bytes      : raw (conv2 output fp32 NCDHW) overwrites xt
    //        [4*NEL, +2KiB)        : st stats block (round-2-proven ws footprint)
    float* out     = (float*)d_out;
    float* off_out = out + NEL;
    unsigned short* out1 = (unsigned short*)d_out;
    unsigned short* wb   = (unsigned short*)(out + 13000000);  // byte 52,000,000
    unsigned short* BtO  = wb;
    unsigned short* Bt1  = BtO + 27648;
    unsigned short* Bt2  = Bt1 + 110592;

    unsigned short* xt  = (unsigned short*)d_ws;
    float*          raw = (float*)d_ws;
    float*          st  = (float*)d_ws + NEL;   // bytes [4*NEL, 4*NEL+2048)
    // st: 0 sum1 | 64 sq1 | 128 sc1 | 192 sh1 | 256 sum2 | 320 sq2 | 384 sc2 | 448 sh2

    hipMemsetAsync(st, 0, 512 * sizeof(float), stream);

    k_transpose<<<dim3(16, 8, 7), 256, 0, stream>>>(x, xt);
    k_wprep<<<432, 256, 0, stream>>>(w_off, w1, w2, BtO, Bt1, Bt2);

    const dim3 cgrid(56, 16, 8);   // h, d, n
    k_conv<8, false><<<cgrid, 256, 0, stream>>>(xt, BtO, b_off, nullptr, nullptr, off_out);
    k_deform<<<cgrid, 256, 0, stream>>>(xt, off_out, Bt1, out1);

    k_stats_bf16<<<392, 256, 0, stream>>>(out1, st + 0, st + 64);
    k_finalize<<<1, 64, 0, stream>>>(st + 0, st + 64, g1, be1, st + 128, st + 192);

    k_conv<64, true><<<cgrid, 256, 0, stream>>>(out1, Bt2, b2, st + 128, st + 192, raw);

    k_stats<<<dim3(64, 8), 256, 0, stream>>>(raw, st + 256, st + 320);
    k_finalize<<<1, 64, 0, stream>>>(st + 256, st + 320, g2, be2, st + 384, st + 448);
    k_residual<<<25088, 256, 0, stream>>>((float4*)out, (const float4*)raw, (const float4*)x, st + 384, st + 448);
}